// Round 13
// baseline (484.858 us; speedup 1.0000x reference)
//
#include <hip/hip_runtime.h>

#define N_NODES 50000
#define N_EDGES 400000
#define EMB 32
#define NREL 8
#define NLAYER 5
#define NPB 16                 // nodes per block = waves per block (1024 threads, 1 node/wave)
#define NBLK (N_NODES / NPB)   // 3125 node-blocks
#define KROWS 43               // 0..31 P, 32 Stot, 33..40 S_r, 41 h_dst(rgcn), 42 h_dst(nn)
#define NCHUNK 196             // ceil(50000/256) scan chunks
#define E2CAP (N_EDGES + 8 * N_NODES)   // 800000: padded edge capacity
#define FCB (N_NODES / 8)               // 6250 fc blocks
#define FILLB ((9 * N_NODES + 255) / 256)   // zero blocks (relcnt+cursor = 9N ints)
#define WTBFB 83

typedef __attribute__((ext_vector_type(8))) short short8;   // 8 bf16 (4 VGPRs)
typedef __attribute__((ext_vector_type(4))) float f32x4;    // MFMA accumulator
typedef __attribute__((ext_vector_type(4))) unsigned int u32x4v;

__device__ __forceinline__ unsigned short f2bf(float f) {   // RNE f32 -> bf16
    unsigned u = __float_as_uint(f);
    unsigned r = u + 0x7FFF + ((u >> 16) & 1);
    return (unsigned short)(r >> 16);
}

// packed RNE f32x2 -> bf16x2 (lo = a, hi = b)
__device__ __forceinline__ unsigned cvt_pk(float a, float b) {
    unsigned r;
    asm("v_cvt_pk_bf16_f32 %0, %1, %2" : "=v"(r) : "v"(a), "v"(b));
    return r;
}

__device__ __forceinline__ int pdeg_of(int d) {   // ceil(max(d,1)/8)*8
    return (d > 0 ? d + 7 : 8) & ~7;
}

// ---------------- fused setup0: fc | zero-fill | wtbf (independent work, one dispatch) --------

__global__ __launch_bounds__(256) void setup0_kernel(
    const float* __restrict__ x, const float* __restrict__ fcW, const float* __restrict__ fcb,
    float* __restrict__ h, unsigned short* __restrict__ hb16,
    int* __restrict__ zero9,                 // relcnt..cursor (9N ints)
    unsigned* __restrict__ hb16a_pad, unsigned* __restrict__ hb16b_pad,
    const float* __restrict__ W2, const float* __restrict__ b2,
    const float* __restrict__ rgcnW, const float* __restrict__ rgcnRoot,
    const float* __restrict__ nnRoot, unsigned short* __restrict__ WB) {
    __shared__ __align__(16) float xt[8][EMB];
    const int b = blockIdx.x, tid = threadIdx.x;
    if (b < FCB) {
        // fc: h0 = relu(x @ fc_W + fc_b); f32 h interleaved (il(c)=2*(c&15)+(c>>4)) + bf16 shadow
        int nl = tid >> 5, lane = tid & 31;
        int n0 = b * 8;
        xt[tid >> 5][tid & 31] = x[n0 * EMB + tid];
        __syncthreads();
        float acc = fcb[lane];
        #pragma unroll
        for (int i = 0; i < EMB; i++) acc += xt[nl][i] * fcW[i * EMB + lane];
        float v = fmaxf(acc, 0.0f);
        int ol = ((lane & 15) << 1) | (lane >> 4);
        h[(size_t)(n0 + nl) * EMB + ol] = v;
        float pv = __shfl_down(v, 16, 32);      // col lane+16 (32-lane segments node-aligned)
        unsigned pk = cvt_pk(v, pv);
        if (lane < 16)
            *(unsigned*)&hb16[(size_t)(n0 + nl) * EMB + 2 * lane] = pk;
    } else if (b < FCB + FILLB) {
        int i = (b - FCB) * 256 + tid;
        if (i < 9 * N_NODES) zero9[i] = 0;
        if (i < EMB / 2) { hb16a_pad[i] = 0u; hb16b_pad[i] = 0u; }  // sentinel rows
    } else {
        // wtbf: transpose+bf16 weights, interleaved-k: i(k) = (k>>1) + ((k&1)<<4)
        int m = b - FCB - FILLB;
        const float* src;
        if (m < 32) src = W2 + (size_t)m * 1024;
        else if (m == 32) src = b2;
        else {
            int t = m - 33, l = t / 10, j = t % 10;
            src = (j < 8) ? rgcnW + (size_t)(l * 8 + j) * 1024
                : (j == 8) ? rgcnRoot + (size_t)l * 1024
                           : nnRoot + (size_t)l * 1024;
        }
        unsigned short* dst = WB + (size_t)m * 1024;
        #pragma unroll
        for (int c = 0; c < 4; c++) {
            int idx = c * 256 + tid;
            int o = idx >> 5, k = idx & 31;
            int i = (k >> 1) + ((k & 1) << 4);
            dst[o * 32 + k] = f2bf(src[i * 32 + o]);
        }
    }
}

// hist: relcnt only (deg derived in nodeprep — halves the atomic count)
__global__ __launch_bounds__(256) void hist_kernel(const int* __restrict__ ei,
                                                   const int* __restrict__ et,
                                                   int* __restrict__ relcnt) {
    int e = blockIdx.x * 256 + threadIdx.x;
    if (e < N_EDGES) {
        int d = ei[N_EDGES + e];           // dst = edge_index[1]
        atomicAdd(&relcnt[d * NREL + et[e]], 1);
    }
}

// fused: deg from relcnt row-sum + per-chunk padded-degree sums + inv tables.
// (CONSECUTIVE 16-node blocks — R7/R9 proved ANY cross-block node permutation
// inflates HBM traffic 2.4x. Single-pass waves need no pairperm.)
__global__ __launch_bounds__(256) void nodeprep_kernel(const int* __restrict__ relcnt,
                                                       int* __restrict__ deg,
                                                       int* __restrict__ bsum,
                                                       float* __restrict__ invdeg,
                                                       float* __restrict__ invcnt) {
    __shared__ int wsum[4];
    int tid = threadIdx.x, lane = tid & 63, wv = tid >> 6;
    int i = blockIdx.x * 256 + tid;
    int d = 0;
    if (i < N_NODES) {
        int c0 = relcnt[i * NREL + 0], c1 = relcnt[i * NREL + 1];
        int c2 = relcnt[i * NREL + 2], c3 = relcnt[i * NREL + 3];
        int c4 = relcnt[i * NREL + 4], c5 = relcnt[i * NREL + 5];
        int c6 = relcnt[i * NREL + 6], c7 = relcnt[i * NREL + 7];
        d = c0 + c1 + c2 + c3 + c4 + c5 + c6 + c7;
        deg[i] = d;
        invdeg[i] = 1.0f / (float)(d > 0 ? d : 1);
        invcnt[i * NREL + 0] = 1.0f / (float)(c0 > 0 ? c0 : 1);
        invcnt[i * NREL + 1] = 1.0f / (float)(c1 > 0 ? c1 : 1);
        invcnt[i * NREL + 2] = 1.0f / (float)(c2 > 0 ? c2 : 1);
        invcnt[i * NREL + 3] = 1.0f / (float)(c3 > 0 ? c3 : 1);
        invcnt[i * NREL + 4] = 1.0f / (float)(c4 > 0 ? c4 : 1);
        invcnt[i * NREL + 5] = 1.0f / (float)(c5 > 0 ? c5 : 1);
        invcnt[i * NREL + 6] = 1.0f / (float)(c6 > 0 ? c6 : 1);
        invcnt[i * NREL + 7] = 1.0f / (float)(c7 > 0 ? c7 : 1);
    }
    int v = (i < N_NODES) ? pdeg_of(d) : 0;
    #pragma unroll
    for (int off = 32; off > 0; off >>= 1) v += __shfl_down(v, off, 64);
    if (lane == 0) wsum[wv] = v;
    __syncthreads();
    if (tid == 0) bsum[blockIdx.x] = wsum[0] + wsum[1] + wsum[2] + wsum[3];
}

// scan chunk sums -> boff; row_ptr[N] = total padded
__global__ __launch_bounds__(256) void boff_kernel(const int* __restrict__ bsum,
                                                   int* __restrict__ boff,
                                                   int* __restrict__ row_ptr) {
    __shared__ int ws[4];
    int tid = threadIdx.x, lane = tid & 63, w = tid >> 6;
    int v = (tid < NCHUNK) ? bsum[tid] : 0;
    int incl = v;
    #pragma unroll
    for (int off = 1; off < 64; off <<= 1) {
        int t = __shfl_up(incl, off, 64);
        if (lane >= off) incl += t;
    }
    if (lane == 63) ws[w] = incl;
    __syncthreads();
    int add = 0;
    for (int j = 0; j < w; j++) add += ws[j];
    if (tid < NCHUNK) boff[tid] = add + incl - v;
    if (tid == 0) row_ptr[N_NODES] = ws[0] + ws[1] + ws[2] + ws[3];
}

// per-chunk exclusive scan (padded degrees) -> row_ptr
__global__ __launch_bounds__(256) void rptr_kernel(const int* __restrict__ deg,
                                                   const int* __restrict__ boff,
                                                   int* __restrict__ row_ptr) {
    __shared__ int ws[4];
    int tid = threadIdx.x, lane = tid & 63, w = tid >> 6;
    int i = blockIdx.x * 256 + tid;
    int v = (i < N_NODES) ? pdeg_of(deg[i]) : 0;
    int incl = v;
    #pragma unroll
    for (int off = 1; off < 64; off <<= 1) {
        int t = __shfl_up(incl, off, 64);
        if (lane >= off) incl += t;
    }
    if (lane == 63) ws[w] = incl;
    __syncthreads();
    int add = boff[blockIdx.x];
    for (int j = 0; j < w; j++) add += ws[j];
    if (i < N_NODES) row_ptr[i] = add + incl - v;
}

// scatter real edges + write each node's own pad sentinels
__global__ __launch_bounds__(256) void scatter_kernel(const int* __restrict__ ei,
                                                      const int* __restrict__ et,
                                                      const float* __restrict__ ed,
                                                      const int* __restrict__ row_ptr,
                                                      const int* __restrict__ deg,
                                                      int* __restrict__ cursor,
                                                      int2* __restrict__ edge2) {
    int e = blockIdx.x * 256 + threadIdx.x;
    if (e < N_EDGES) {
        int d = ei[N_EDGES + e];
        int pos = row_ptr[d] + atomicAdd(&cursor[d], 1);
        edge2[pos] = make_int2(ei[e] | (et[e] << 16), __float_as_int(ed[e]));
    }
    if (e < N_NODES) {
        int base = row_ptr[e], d = deg[e], pd = pdeg_of(d);
        for (int p = base + d; p < base + pd; ++p)
            edge2[p] = make_int2(N_NODES, 0);          // sentinel -> zero hb16 row
    }
}

// ---------------- fused layer kernel (single-pass waves, full occupancy) ----------------
// 1024 threads = 16 waves, ONE consecutive node per wave. __launch_bounds__(1024,4):
// VGPR budget 128 (kernel needs ~40 -> NO spill; R6's (1024,8) budget-64 spill avoided),
// residency 2 blocks/CU = 32 waves = 100% occupancy. Half the serial latency chains of
// the 2-pass shape. bf16-shadow gathers (R10); padded CSR sentinels; wave-uniform jp
// guards; jp0 prefetch before barrier (1-quad live-range budget — R11 spill lesson).
// wrb2f stride 17 float2/relation: spreads random-ra reads across banks (kills the
// persistent 2.4M LDS conflicts; stride 16 put every quad on bank 2m).

__device__ __forceinline__ void gath(const unsigned short* __restrict__ hb16, int4 E, int m,
                                     unsigned& uA, unsigned& uB) {
    uA = *(const unsigned*)(hb16 + (((size_t)(E.x & 0xFFFF)) << 5) + 2 * m);
    uB = *(const unsigned*)(hb16 + (((size_t)(E.z & 0xFFFF)) << 5) + 2 * m);
}

__device__ __forceinline__ void proc_pair(int4 E, unsigned uA, unsigned uB,
                                          const float2* wrb2f, float w10_0, float w10_1,
                                          unsigned selm, int m,
                                          unsigned& A0s, unsigned& A1s, unsigned& ASs,
                                          unsigned& B0s, unsigned& B1s) {
    int ra = (E.x >> 16) & 7, rb = (E.z >> 16) & 7;
    float2 wa = wrb2f[ra * 17 + m];
    float2 wb = wrb2f[rb * 17 + m];
    float da = __int_as_float(E.y), db = __int_as_float(E.w);
    float hA0 = fmaxf(fmaf(da, w10_0, wa.x), 0.f);
    float hA1 = fmaxf(fmaf(da, w10_1, wa.y), 0.f);
    float hB0 = fmaxf(fmaf(db, w10_0, wb.x), 0.f);
    float hB1 = fmaxf(fmaf(db, w10_1, wb.y), 0.f);
    A0s = cvt_pk(hA0, hB0);
    A1s = cvt_pk(hA1, hB1);
    ASs = cvt_pk((float)((selm >> ra) & 1u), (float)((selm >> rb) & 1u));
    B0s = (uA & 0xFFFFu) | (uB << 16);          // k-slots (2jp lo, 2jp+1 hi), col m
    B1s = (uA >> 16) | (uB & 0xFFFF0000u);      // col m+16
}

__device__ __forceinline__ void mfma6(const unsigned* fa0v, const unsigned* fa1v,
                                      const unsigned* fasv, const unsigned* fb0v,
                                      const unsigned* fb1v,
                                      f32x4& aP00, f32x4& aP01, f32x4& aP10, f32x4& aP11,
                                      f32x4& aS0, f32x4& aS1) {
    u32x4v u0 = {fa0v[0], fa0v[1], fa0v[2], fa0v[3]};
    u32x4v u1 = {fa1v[0], fa1v[1], fa1v[2], fa1v[3]};
    u32x4v us = {fasv[0], fasv[1], fasv[2], fasv[3]};
    u32x4v v0 = {fb0v[0], fb0v[1], fb0v[2], fb0v[3]};
    u32x4v v1 = {fb1v[0], fb1v[1], fb1v[2], fb1v[3]};
    short8 A0 = __builtin_bit_cast(short8, u0);
    short8 A1 = __builtin_bit_cast(short8, u1);
    short8 AS = __builtin_bit_cast(short8, us);
    short8 B0 = __builtin_bit_cast(short8, v0);
    short8 B1 = __builtin_bit_cast(short8, v1);
    aP00 = __builtin_amdgcn_mfma_f32_16x16x32_bf16(A0, B0, aP00, 0, 0, 0);
    aP01 = __builtin_amdgcn_mfma_f32_16x16x32_bf16(A0, B1, aP01, 0, 0, 0);
    aP10 = __builtin_amdgcn_mfma_f32_16x16x32_bf16(A1, B0, aP10, 0, 0, 0);
    aP11 = __builtin_amdgcn_mfma_f32_16x16x32_bf16(A1, B1, aP11, 0, 0, 0);
    aS0  = __builtin_amdgcn_mfma_f32_16x16x32_bf16(AS, B0, aS0, 0, 0, 0);
    aS1  = __builtin_amdgcn_mfma_f32_16x16x32_bf16(AS, B1, aS1, 0, 0, 0);
}

__device__ __forceinline__ void edge_pass(const unsigned short* __restrict__ hb16,
                                          const int2* __restrict__ edge2,
                                          const float2* wrb2f,
                                          int pb, int pe, int quad, int m,
                                          float w10_0, float w10_1, unsigned selm,
                                          int4 E0, unsigned u0A, unsigned u0B,
                                          f32x4& aP00, f32x4& aP01, f32x4& aP10,
                                          f32x4& aP11, f32x4& aS0, f32x4& aS1) {
    {   // first chunk: jp0 from prefetch, jp1..3 dependent (wave-uniform guards)
        unsigned fa0v[4] = {0,0,0,0}, fa1v[4] = {0,0,0,0}, fasv[4] = {0,0,0,0};
        unsigned fb0v[4] = {0,0,0,0}, fb1v[4] = {0,0,0,0};
        proc_pair(E0, u0A, u0B, wrb2f, w10_0, w10_1, selm, m,
                  fa0v[0], fa1v[0], fasv[0], fb0v[0], fb1v[0]);
        if (pb + 8 < pe) {
            int4 E = *(const int4*)&edge2[pb + 8 + quad * 2];
            unsigned uA, uB; gath(hb16, E, m, uA, uB);
            proc_pair(E, uA, uB, wrb2f, w10_0, w10_1, selm, m,
                      fa0v[1], fa1v[1], fasv[1], fb0v[1], fb1v[1]);
        }
        if (pb + 16 < pe) {
            int4 E = *(const int4*)&edge2[pb + 16 + quad * 2];
            unsigned uA, uB; gath(hb16, E, m, uA, uB);
            proc_pair(E, uA, uB, wrb2f, w10_0, w10_1, selm, m,
                      fa0v[2], fa1v[2], fasv[2], fb0v[2], fb1v[2]);
        }
        if (pb + 24 < pe) {
            int4 E = *(const int4*)&edge2[pb + 24 + quad * 2];
            unsigned uA, uB; gath(hb16, E, m, uA, uB);
            proc_pair(E, uA, uB, wrb2f, w10_0, w10_1, selm, m,
                      fa0v[3], fa1v[3], fasv[3], fb0v[3], fb1v[3]);
        }
        mfma6(fa0v, fa1v, fasv, fb0v, fb1v, aP00, aP01, aP10, aP11, aS0, aS1);
    }
    for (int c0 = pb + 32; c0 < pe; c0 += 32) {   // rare (pdeg > 32)
        unsigned fa0v[4] = {0,0,0,0}, fa1v[4] = {0,0,0,0}, fasv[4] = {0,0,0,0};
        unsigned fb0v[4] = {0,0,0,0}, fb1v[4] = {0,0,0,0};
        #pragma unroll
        for (int jp = 0; jp < 4; ++jp) {
            if (c0 + jp * 8 < pe) {
                int4 E = *(const int4*)&edge2[c0 + jp * 8 + quad * 2];
                unsigned uA, uB; gath(hb16, E, m, uA, uB);
                proc_pair(E, uA, uB, wrb2f, w10_0, w10_1, selm, m,
                          fa0v[jp], fa1v[jp], fasv[jp], fb0v[jp], fb1v[jp]);
            }
        }
        mfma6(fa0v, fa1v, fasv, fb0v, fb1v, aP00, aP01, aP10, aP11, aS0, aS1);
    }
}

__device__ __forceinline__ void stage_node(unsigned short* __restrict__ P, int quad, int m,
                                           float idg, const float* __restrict__ invcnt_n,
                                           const unsigned short* __restrict__ hb16row,
                                           const f32x4& aP00, const f32x4& aP01,
                                           const f32x4& aP10, const f32x4& aP11,
                                           const f32x4& aS0, const f32x4& aS1) {
    #pragma unroll
    for (int reg = 0; reg < 4; ++reg) {
        const int row = quad * 4 + reg;       // D: row = quad*4+reg, col = m / m+16
        *(unsigned*)&P[row * EMB + 2 * m]        = cvt_pk(aP00[reg] * idg, aP01[reg] * idg);
        *(unsigned*)&P[(row + 16) * EMB + 2 * m] = cvt_pk(aP10[reg] * idg, aP11[reg] * idg);
        if (row <= 8) {                        // S rows: 0 -> Stot(32), 1..8 -> S_r(33..40)
            const float sc = (row == 0) ? idg : invcnt_n[row - 1];
            *(unsigned*)&P[(32 + row) * EMB + 2 * m] = cvt_pk(aS0[reg] * sc, aS1[reg] * sc);
        }
    }
    if (quad < 2) {                            // rows 41/42: h_dst direct from bf16 shadow
        unsigned hh = *(const unsigned*)(hb16row + 2 * m);
        *(unsigned*)&P[(41 + quad) * EMB + 2 * m] = hh;
    }
}

__global__ __launch_bounds__(1024, 4) void layer_kernel(
    const float* __restrict__ h,
    const unsigned short* __restrict__ hb16,
    const int2* __restrict__ edge2,
    const int* __restrict__ row_ptr,
    const float* __restrict__ invdeg,
    const float* __restrict__ invcnt,
    const float* __restrict__ W1,
    const float* __restrict__ b1,
    const unsigned short* __restrict__ WBs,   // rows 0..32 (W2^T, b2^T)
    const unsigned short* __restrict__ WBl,   // rows 33..42
    const float* __restrict__ rgcnBias_l,
    const float* __restrict__ nnBias_l,
    float* __restrict__ hout,
    unsigned short* __restrict__ hb16out,
    int last)
{
    __shared__ __align__(16) unsigned short P_lds[NPB * KROWS * EMB];  // 44032 B
    __shared__ __align__(16) float2 wrb2f[NREL * 17];                  // 1088 B (stride 17)
    // total ~45152 B; residency wave-capped at 2 blocks/CU (32 waves, 100%)

    const int tid = threadIdx.x;
    const int n0 = blockIdx.x * NPB;

    if (tid < 128) {
        int r = tid >> 4, mi = tid & 15;
        wrb2f[r * 17 + mi] = make_float2(W1[(1 + r) * EMB + mi] + b1[mi],
                                         W1[(1 + r) * EMB + mi + 16] + b1[mi + 16]);
    }

    const int l    = tid & 63;
    const int w    = tid >> 6;        // wave 0..15 = node slot
    const int quad = l >> 4;          // 0..3
    const int m    = l & 15;
    const float w10_0 = W1[m];
    const float w10_1 = W1[m + 16];
    const unsigned selm = (m == 0) ? 0xFFu : (m <= 8 ? (1u << (m - 1)) : 0u);

    const int n  = n0 + w;            // this wave's node (consecutive)
    const int pb = row_ptr[n], pe = row_ptr[n + 1];   // padded bounds (pe-pb = pdeg)
    // prefetch jp0 edge-quad + gather before the barrier (1-quad budget — R11 lesson)
    int4 E0 = *(const int4*)&edge2[pb + quad * 2];
    unsigned u0A, u0B;
    gath(hb16, E0, m, u0A, u0B);

    __syncthreads();   // wrb2f ready

    {   // single edge pass
        f32x4 aP00 = {0,0,0,0}, aP01 = {0,0,0,0}, aP10 = {0,0,0,0}, aP11 = {0,0,0,0};
        f32x4 aS0 = {0,0,0,0}, aS1 = {0,0,0,0};
        edge_pass(hb16, edge2, wrb2f, pb, pe, quad, m, w10_0, w10_1, selm,
                  E0, u0A, u0B, aP00, aP01, aP10, aP11, aS0, aS1);
        stage_node(P_lds + (size_t)w * KROWS * EMB, quad, m, invdeg[n],
                   invcnt + (size_t)n * NREL, hb16 + (size_t)n * EMB,
                   aP00, aP01, aP10, aP11, aS0, aS1);
    }
    __syncthreads();

    // ---------- MFMA contraction: 16 waves x up-to-3 rows ----------
    const int node16 = l & 15;
    const int o0 = l & 15;                    // B n-index (tile 0); tile 1 = +16

    f32x4 accN0 = {0,0,0,0}, accN1 = {0,0,0,0};
    f32x4 accR0 = {0,0,0,0}, accR1 = {0,0,0,0};

    #pragma unroll
    for (int j = 0; j < 3; j++) {
        const int rr = w + 16 * j;            // wave-uniform
        if (rr < KROWS) {
            const unsigned short* Bsrc = (rr < 33) ? (WBs + (size_t)rr * 1024)
                                                   : (WBl + (size_t)(rr - 33) * 1024);
            short8 bf0 = *(const short8*)(Bsrc + o0 * 32 + quad * 8);
            short8 bf1 = *(const short8*)(Bsrc + (o0 + 16) * 32 + quad * 8);
            short8 a = *(const short8*)&P_lds[(size_t)node16 * KROWS * EMB + rr * EMB + quad * 8];
            if (rr <= 32 || rr == 42) {
                accN0 = __builtin_amdgcn_mfma_f32_16x16x32_bf16(a, bf0, accN0, 0, 0, 0);
                accN1 = __builtin_amdgcn_mfma_f32_16x16x32_bf16(a, bf1, accN1, 0, 0, 0);
            } else {
                accR0 = __builtin_amdgcn_mfma_f32_16x16x32_bf16(a, bf0, accR0, 0, 0, 0);
                accR1 = __builtin_amdgcn_mfma_f32_16x16x32_bf16(a, bf1, accR1, 0, 0, 0);
            }
        }
    }
    __syncthreads();                          // all A-reads done; safe to overlay RedAll

    // ---------- deterministic cross-wave reduction (2 rounds, no atomics — R6-verified) -------
    float* RedAll = (float*)&P_lds[0];        // 8 slots x 1024 floats = 32 KiB < 44 KiB
    if (w < 8) {                              // round A: waves 0-7 write their slot
        float* my = RedAll + w * 1024;
        #pragma unroll
        for (int reg = 0; reg < 4; reg++) {
            int nd = quad * 4 + reg;          // C/D: row(m=node)=quad*4+reg, col(n=o)=lane&15
            my[nd * 32 + o0]            = accN0[reg];
            my[nd * 32 + o0 + 16]       = accN1[reg];
            my[512 + nd * 32 + o0]      = accR0[reg];
            my[512 + nd * 32 + o0 + 16] = accR1[reg];
        }
    }
    __syncthreads();
    if (w >= 8) {                             // round B: waves 8-15 add into slot w-8
        float* my = RedAll + (w - 8) * 1024;
        #pragma unroll
        for (int reg = 0; reg < 4; reg++) {
            int nd = quad * 4 + reg;
            my[nd * 32 + o0]            += accN0[reg];
            my[nd * 32 + o0 + 16]       += accN1[reg];
            my[512 + nd * 32 + o0]      += accR0[reg];
            my[512 + nd * 32 + o0 + 16] += accR1[reg];
        }
    }
    __syncthreads();

    // ---------- epilogue: threads 0..511 (slot = tid>>5, node = n0+slot, col = tid&31) -------
    if (tid < 512) {
        const int hw2 = tid >> 5, lane = tid & 31;
        const int n2 = n0 + hw2;
        float sn = 0.0f, sr = 0.0f;
        #pragma unroll
        for (int ww = 0; ww < 8; ww++) {
            sn += RedAll[ww * 1024 + tid];          // stride-1, conflict-free
            sr += RedAll[ww * 1024 + 512 + tid];
        }
        const int il = ((lane & 15) << 1) | (lane >> 4);
        float hd = h[(size_t)n2 * EMB + il];
        float o_r = fmaxf(sr + rgcnBias_l[lane], 0.0f);
        float o_n = fmaxf(sn + nnBias_l[lane], 0.0f);
        float outv = hd + o_r + o_n;
        hout[(size_t)n2 * EMB + (last ? lane : il)] = outv;
        if (!last) {                               // bf16 shadow for next layer's gathers
            float pv = __shfl_down(outv, 16, 32);  // col lane+16 (32-lane segs node-aligned)
            unsigned pk = cvt_pk(outv, pv);
            if (lane < 16)
                *(unsigned*)&hb16out[(size_t)n2 * EMB + 2 * lane] = pk;
        }
    }
}

// ---------------- launch ----------------

extern "C" void kernel_launch(void* const* d_in, const int* in_sizes, int n_in,
                              void* d_out, int out_size, void* d_ws, size_t ws_size,
                              hipStream_t stream) {
    const float* x        = (const float*)d_in[0];
    const int*   ei       = (const int*)d_in[1];
    const int*   et       = (const int*)d_in[2];
    const float* ed       = (const float*)d_in[3];
    const float* fcW      = (const float*)d_in[4];
    const float* fcb      = (const float*)d_in[5];
    const float* rgcnW    = (const float*)d_in[6];
    const float* rgcnRoot = (const float*)d_in[7];
    const float* rgcnBias = (const float*)d_in[8];
    const float* W1       = (const float*)d_in[9];
    const float* b1       = (const float*)d_in[10];
    const float* W2       = (const float*)d_in[11];
    const float* b2       = (const float*)d_in[12];
    const float* nnRoot   = (const float*)d_in[13];
    const float* nnBias   = (const float*)d_in[14];

    float* ws = (float*)d_ws;
    float* h_a    = ws;  ws += (size_t)(N_NODES + 1) * EMB;
    float* h_b    = ws;  ws += (size_t)(N_NODES + 1) * EMB;
    unsigned short* hb16_a = (unsigned short*)ws;  ws += (size_t)(N_NODES + 1) * EMB / 2;
    unsigned short* hb16_b = (unsigned short*)ws;  ws += (size_t)(N_NODES + 1) * EMB / 2;
    float* invdeg = ws;  ws += (size_t)N_NODES;
    float* invcnt = ws;  ws += (size_t)N_NODES * NREL;
    unsigned short* WB = (unsigned short*)ws;  ws += (size_t)83 * 1024 / 2;
    int2* edge2   = (int2*)ws;     ws += (size_t)E2CAP * 2;
    int* row_ptr  = (int*)ws;      ws += (size_t)(N_NODES + 1);
    int* bsum     = (int*)ws;      ws += (size_t)NCHUNK;
    int* boff     = (int*)ws;      ws += (size_t)NCHUNK;
    int* deg      = (int*)ws;      ws += (size_t)N_NODES;     // written by nodeprep (no zero)
    int* relcnt   = (int*)ws;      ws += (size_t)N_NODES * NREL;  // relcnt..cursor zeroed (9N)
    int* cursor   = (int*)ws;      ws += (size_t)N_NODES;
    (void)in_sizes; (void)n_in; (void)out_size; (void)ws_size;

    setup0_kernel<<<FCB + FILLB + WTBFB, 256, 0, stream>>>(
        x, fcW, fcb, h_a, hb16_a, relcnt,
        (unsigned*)(hb16_a + (size_t)N_NODES * EMB),
        (unsigned*)(hb16_b + (size_t)N_NODES * EMB),
        W2, b2, rgcnW, rgcnRoot, nnRoot, WB);
    hist_kernel<<<(N_EDGES + 255) / 256, 256, 0, stream>>>(ei, et, relcnt);
    nodeprep_kernel<<<NCHUNK, 256, 0, stream>>>(relcnt, deg, bsum, invdeg, invcnt);
    boff_kernel<<<1, 256, 0, stream>>>(bsum, boff, row_ptr);
    rptr_kernel<<<NCHUNK, 256, 0, stream>>>(deg, boff, row_ptr);
    scatter_kernel<<<(N_EDGES + 255) / 256, 256, 0, stream>>>(ei, et, ed, row_ptr, deg,
                                                              cursor, edge2);

    const float* hin = h_a;
    const unsigned short* hbin = hb16_a;
    float* houtb = h_b;
    unsigned short* hboutb = hb16_b;
    for (int l = 0; l < NLAYER; l++) {
        int last = (l == NLAYER - 1) ? 1 : 0;
        float* dst = last ? (float*)d_out : houtb;
        layer_kernel<<<NBLK, 1024, 0, stream>>>(
            hin, hbin, edge2, row_ptr, invdeg, invcnt, W1, b1,
            WB, WB + (size_t)(33 + l * 10) * 1024,
            rgcnBias + (size_t)l * EMB,
            nnBias + (size_t)l * EMB,
            dst, hboutb, last);
        float* old_in = (float*)hin;
        unsigned short* old_hb = (unsigned short*)hbin;
        hin = dst; hbin = hboutb;
        houtb = old_in; hboutb = old_hb;
    }
}

// Round 14
// 367.768 us; speedup vs baseline: 1.3184x; 1.3184x over previous
//
#include <hip/hip_runtime.h>

#define N_NODES 50000
#define N_EDGES 400000
#define EMB 32
#define NREL 8
#define NLAYER 5
#define NPB 16                 // nodes per block (8 waves x 2 balanced passes, 512 threads)
#define NBLK (N_NODES / NPB)   // 3125 node-blocks
#define KROWS 43               // 0..31 P, 32 Stot, 33..40 S_r, 41 h_dst(rgcn), 42 h_dst(nn)
#define NCHUNK 196             // ceil(50000/256) scan chunks
#define E2CAP (N_EDGES + 8 * N_NODES)   // 800000: padded edge capacity
#define FCB (N_NODES / 8)               // 6250 fc blocks
#define FILLB ((9 * N_NODES + 255) / 256)   // zero blocks (relcnt+cursor = 9N ints)
#define WTBFB 83

typedef __attribute__((ext_vector_type(8))) short short8;   // 8 bf16 (4 VGPRs)
typedef __attribute__((ext_vector_type(4))) float f32x4;    // MFMA accumulator
typedef __attribute__((ext_vector_type(4))) unsigned int u32x4v;

__device__ __forceinline__ unsigned short f2bf(float f) {   // RNE f32 -> bf16
    unsigned u = __float_as_uint(f);
    unsigned r = u + 0x7FFF + ((u >> 16) & 1);
    return (unsigned short)(r >> 16);
}

// packed RNE f32x2 -> bf16x2 (lo = a, hi = b)
__device__ __forceinline__ unsigned cvt_pk(float a, float b) {
    unsigned r;
    asm("v_cvt_pk_bf16_f32 %0, %1, %2" : "=v"(r) : "v"(a), "v"(b));
    return r;
}

__device__ __forceinline__ int pdeg_of(int d) {   // ceil(max(d,1)/8)*8
    return (d > 0 ? d + 7 : 8) & ~7;
}

// ---------------- fused setup0: fc | zero-fill | wtbf (independent work, one dispatch) --------

__global__ __launch_bounds__(256) void setup0_kernel(
    const float* __restrict__ x, const float* __restrict__ fcW, const float* __restrict__ fcb,
    float* __restrict__ h, unsigned short* __restrict__ hb16,
    int* __restrict__ zero9,                 // relcnt..cursor (9N ints)
    unsigned* __restrict__ hb16a_pad, unsigned* __restrict__ hb16b_pad,
    const float* __restrict__ W2, const float* __restrict__ b2,
    const float* __restrict__ rgcnW, const float* __restrict__ rgcnRoot,
    const float* __restrict__ nnRoot, unsigned short* __restrict__ WB) {
    __shared__ __align__(16) float xt[8][EMB];
    const int b = blockIdx.x, tid = threadIdx.x;
    if (b < FCB) {
        // fc: h0 = relu(x @ fc_W + fc_b); f32 h interleaved (il(c)=2*(c&15)+(c>>4)) + bf16 shadow
        int nl = tid >> 5, lane = tid & 31;
        int n0 = b * 8;
        xt[tid >> 5][tid & 31] = x[n0 * EMB + tid];
        __syncthreads();
        float acc = fcb[lane];
        #pragma unroll
        for (int i = 0; i < EMB; i++) acc += xt[nl][i] * fcW[i * EMB + lane];
        float v = fmaxf(acc, 0.0f);
        int ol = ((lane & 15) << 1) | (lane >> 4);
        h[(size_t)(n0 + nl) * EMB + ol] = v;
        float pv = __shfl_down(v, 16, 32);      // col lane+16 (32-lane segments node-aligned)
        unsigned pk = cvt_pk(v, pv);
        if (lane < 16)
            *(unsigned*)&hb16[(size_t)(n0 + nl) * EMB + 2 * lane] = pk;
    } else if (b < FCB + FILLB) {
        int i = (b - FCB) * 256 + tid;
        if (i < 9 * N_NODES) zero9[i] = 0;
        if (i < EMB / 2) { hb16a_pad[i] = 0u; hb16b_pad[i] = 0u; }  // sentinel rows
    } else {
        // wtbf: transpose+bf16 weights, interleaved-k: i(k) = (k>>1) + ((k&1)<<4)
        int m = b - FCB - FILLB;
        const float* src;
        if (m < 32) src = W2 + (size_t)m * 1024;
        else if (m == 32) src = b2;
        else {
            int t = m - 33, l = t / 10, j = t % 10;
            src = (j < 8) ? rgcnW + (size_t)(l * 8 + j) * 1024
                : (j == 8) ? rgcnRoot + (size_t)l * 1024
                           : nnRoot + (size_t)l * 1024;
        }
        unsigned short* dst = WB + (size_t)m * 1024;
        #pragma unroll
        for (int c = 0; c < 4; c++) {
            int idx = c * 256 + tid;
            int o = idx >> 5, k = idx & 31;
            int i = (k >> 1) + ((k & 1) << 4);
            dst[o * 32 + k] = f2bf(src[i * 32 + o]);
        }
    }
}

// hist: relcnt only (deg derived in nodeprep — halves the atomic count)
__global__ __launch_bounds__(256) void hist_kernel(const int* __restrict__ ei,
                                                   const int* __restrict__ et,
                                                   int* __restrict__ relcnt) {
    int e = blockIdx.x * 256 + threadIdx.x;
    if (e < N_EDGES) {
        int d = ei[N_EDGES + e];           // dst = edge_index[1]
        atomicAdd(&relcnt[d * NREL + et[e]], 1);
    }
}

// fused: deg from relcnt row-sum + per-chunk padded-degree sums + inv tables + pairperm.
// (R4 schedule: CONSECUTIVE 16-node blocks — R7/R9 proved ANY cross-block node
// permutation inflates HBM traffic 2.4x; balance only via within-block slot pairing.)
__global__ __launch_bounds__(256) void nodeprep_kernel(const int* __restrict__ relcnt,
                                                       int* __restrict__ deg,
                                                       int* __restrict__ bsum,
                                                       float* __restrict__ invdeg,
                                                       float* __restrict__ invcnt,
                                                       unsigned char* __restrict__ perm) {
    __shared__ int wsum[4];
    int tid = threadIdx.x, lane = tid & 63, wv = tid >> 6;
    int i = blockIdx.x * 256 + tid;
    int d = 0;
    if (i < N_NODES) {
        int c0 = relcnt[i * NREL + 0], c1 = relcnt[i * NREL + 1];
        int c2 = relcnt[i * NREL + 2], c3 = relcnt[i * NREL + 3];
        int c4 = relcnt[i * NREL + 4], c5 = relcnt[i * NREL + 5];
        int c6 = relcnt[i * NREL + 6], c7 = relcnt[i * NREL + 7];
        d = c0 + c1 + c2 + c3 + c4 + c5 + c6 + c7;
        deg[i] = d;
        invdeg[i] = 1.0f / (float)(d > 0 ? d : 1);
        invcnt[i * NREL + 0] = 1.0f / (float)(c0 > 0 ? c0 : 1);
        invcnt[i * NREL + 1] = 1.0f / (float)(c1 > 0 ? c1 : 1);
        invcnt[i * NREL + 2] = 1.0f / (float)(c2 > 0 ? c2 : 1);
        invcnt[i * NREL + 3] = 1.0f / (float)(c3 > 0 ? c3 : 1);
        invcnt[i * NREL + 4] = 1.0f / (float)(c4 > 0 ? c4 : 1);
        invcnt[i * NREL + 5] = 1.0f / (float)(c5 > 0 ? c5 : 1);
        invcnt[i * NREL + 6] = 1.0f / (float)(c6 > 0 ? c6 : 1);
        invcnt[i * NREL + 7] = 1.0f / (float)(c7 > 0 ? c7 : 1);
    }
    int v = (i < N_NODES) ? pdeg_of(d) : 0;
    #pragma unroll
    for (int off = 32; off > 0; off >>= 1) v += __shfl_down(v, off, 64);
    if (lane == 0) wsum[wv] = v;
    __syncthreads();
    if (tid == 0) bsum[blockIdx.x] = wsum[0] + wsum[1] + wsum[2] + wsum[3];
    if (i < NBLK) {   // pairperm: degrees recomputed from relcnt (deg[] not yet visible cross-block)
        int dd[NPB]; unsigned char idx[NPB];
        #pragma unroll
        for (int k = 0; k < NPB; k++) {
            int s = 0;
            #pragma unroll
            for (int r = 0; r < NREL; r++) s += relcnt[(i * NPB + k) * NREL + r];
            dd[k] = s; idx[k] = (unsigned char)k;
        }
        for (int a = 1; a < NPB; a++) {          // insertion sort, desc, stable
            int dv = dd[a]; unsigned char iv = idx[a];
            int j = a - 1;
            while (j >= 0 && dd[j] < dv) { dd[j + 1] = dd[j]; idx[j + 1] = idx[j]; j--; }
            dd[j + 1] = dv; idx[j + 1] = iv;
        }
        #pragma unroll
        for (int k = 0; k < NPB; k++) perm[i * NPB + k] = idx[k];
    }
}

// scan chunk sums -> boff; row_ptr[N] = total padded
__global__ __launch_bounds__(256) void boff_kernel(const int* __restrict__ bsum,
                                                   int* __restrict__ boff,
                                                   int* __restrict__ row_ptr) {
    __shared__ int ws[4];
    int tid = threadIdx.x, lane = tid & 63, w = tid >> 6;
    int v = (tid < NCHUNK) ? bsum[tid] : 0;
    int incl = v;
    #pragma unroll
    for (int off = 1; off < 64; off <<= 1) {
        int t = __shfl_up(incl, off, 64);
        if (lane >= off) incl += t;
    }
    if (lane == 63) ws[w] = incl;
    __syncthreads();
    int add = 0;
    for (int j = 0; j < w; j++) add += ws[j];
    if (tid < NCHUNK) boff[tid] = add + incl - v;
    if (tid == 0) row_ptr[N_NODES] = ws[0] + ws[1] + ws[2] + ws[3];
}

// per-chunk exclusive scan (padded degrees) -> row_ptr
__global__ __launch_bounds__(256) void rptr_kernel(const int* __restrict__ deg,
                                                   const int* __restrict__ boff,
                                                   int* __restrict__ row_ptr) {
    __shared__ int ws[4];
    int tid = threadIdx.x, lane = tid & 63, w = tid >> 6;
    int i = blockIdx.x * 256 + tid;
    int v = (i < N_NODES) ? pdeg_of(deg[i]) : 0;
    int incl = v;
    #pragma unroll
    for (int off = 1; off < 64; off <<= 1) {
        int t = __shfl_up(incl, off, 64);
        if (lane >= off) incl += t;
    }
    if (lane == 63) ws[w] = incl;
    __syncthreads();
    int add = boff[blockIdx.x];
    for (int j = 0; j < w; j++) add += ws[j];
    if (i < N_NODES) row_ptr[i] = add + incl - v;
}

// scatter real edges + write each node's own pad sentinels + build wavetab.
// wavetab[b*8+w] = {s0 | s1<<8, pb0, pb1, pd0 | pd1<<16}; slots from pairperm.
__global__ __launch_bounds__(256) void scatter_kernel(const int* __restrict__ ei,
                                                      const int* __restrict__ et,
                                                      const float* __restrict__ ed,
                                                      const int* __restrict__ row_ptr,
                                                      const int* __restrict__ deg,
                                                      int* __restrict__ cursor,
                                                      int2* __restrict__ edge2,
                                                      const unsigned char* __restrict__ perm,
                                                      int4* __restrict__ wavetab) {
    int e = blockIdx.x * 256 + threadIdx.x;
    if (e < N_EDGES) {
        int d = ei[N_EDGES + e];
        int pos = row_ptr[d] + atomicAdd(&cursor[d], 1);
        edge2[pos] = make_int2(ei[e] | (et[e] << 16), __float_as_int(ed[e]));
    }
    if (e < N_NODES) {
        int base = row_ptr[e], d = deg[e], pd = pdeg_of(d);
        for (int p = base + d; p < base + pd; ++p)
            edge2[p] = make_int2(N_NODES, 0);          // sentinel -> zero hb16 row
    }
    if (e < NBLK * 8) {
        int b = e >> 3, wv = e & 7;
        int s0 = perm[b * NPB + wv], s1 = perm[b * NPB + (NPB - 1 - wv)];
        int nA = b * NPB + s0, nB = b * NPB + s1;
        int pb0 = row_ptr[nA], pd0 = row_ptr[nA + 1] - pb0;
        int pb1 = row_ptr[nB], pd1 = row_ptr[nB + 1] - pb1;
        wavetab[e] = make_int4(s0 | (s1 << 8), pb0, pb1, pd0 | (pd1 << 16));
    }
}

// ---------------- fused layer kernel (R12 body + barrier-free wrb2f init) ----------------
// R4 structure: 512 threads, 8 waves x 2 passes, consecutive 16-node blocks,
// pairperm slot balance, padded CSR (sentinels -> zero row), wave-uniform jp guards.
// bf16-shadow gathers (R10). Prefetch = jp0 of both passes ONLY (R11 spill lesson).
// NEW: wrb2f is written REDUNDANTLY by every wave (2 entries/lane, identical values;
// benign write-write overlap) -> each wave's reads ordered by its own lgkmcnt, so the
// leading __syncthreads() and its convoy are gone (3 barriers instead of 4).

__device__ __forceinline__ void gath(const unsigned short* __restrict__ hb16, int4 E, int m,
                                     unsigned& uA, unsigned& uB) {
    uA = *(const unsigned*)(hb16 + (((size_t)(E.x & 0xFFFF)) << 5) + 2 * m);
    uB = *(const unsigned*)(hb16 + (((size_t)(E.z & 0xFFFF)) << 5) + 2 * m);
}

__device__ __forceinline__ void proc_pair(int4 E, unsigned uA, unsigned uB,
                                          const float2* wrb2f, float w10_0, float w10_1,
                                          unsigned selm, int m,
                                          unsigned& A0s, unsigned& A1s, unsigned& ASs,
                                          unsigned& B0s, unsigned& B1s) {
    int ra = (E.x >> 16) & 7, rb = (E.z >> 16) & 7;
    float2 wa = wrb2f[ra * 16 + m];
    float2 wb = wrb2f[rb * 16 + m];
    float da = __int_as_float(E.y), db = __int_as_float(E.w);
    float hA0 = fmaxf(fmaf(da, w10_0, wa.x), 0.f);
    float hA1 = fmaxf(fmaf(da, w10_1, wa.y), 0.f);
    float hB0 = fmaxf(fmaf(db, w10_0, wb.x), 0.f);
    float hB1 = fmaxf(fmaf(db, w10_1, wb.y), 0.f);
    A0s = cvt_pk(hA0, hB0);
    A1s = cvt_pk(hA1, hB1);
    ASs = cvt_pk((float)((selm >> ra) & 1u), (float)((selm >> rb) & 1u));
    B0s = (uA & 0xFFFFu) | (uB << 16);          // k-slots (2jp lo, 2jp+1 hi), col m
    B1s = (uA >> 16) | (uB & 0xFFFF0000u);      // col m+16
}

__device__ __forceinline__ void mfma6(const unsigned* fa0v, const unsigned* fa1v,
                                      const unsigned* fasv, const unsigned* fb0v,
                                      const unsigned* fb1v,
                                      f32x4& aP00, f32x4& aP01, f32x4& aP10, f32x4& aP11,
                                      f32x4& aS0, f32x4& aS1) {
    u32x4v u0 = {fa0v[0], fa0v[1], fa0v[2], fa0v[3]};
    u32x4v u1 = {fa1v[0], fa1v[1], fa1v[2], fa1v[3]};
    u32x4v us = {fasv[0], fasv[1], fasv[2], fasv[3]};
    u32x4v v0 = {fb0v[0], fb0v[1], fb0v[2], fb0v[3]};
    u32x4v v1 = {fb1v[0], fb1v[1], fb1v[2], fb1v[3]};
    short8 A0 = __builtin_bit_cast(short8, u0);
    short8 A1 = __builtin_bit_cast(short8, u1);
    short8 AS = __builtin_bit_cast(short8, us);
    short8 B0 = __builtin_bit_cast(short8, v0);
    short8 B1 = __builtin_bit_cast(short8, v1);
    aP00 = __builtin_amdgcn_mfma_f32_16x16x32_bf16(A0, B0, aP00, 0, 0, 0);
    aP01 = __builtin_amdgcn_mfma_f32_16x16x32_bf16(A0, B1, aP01, 0, 0, 0);
    aP10 = __builtin_amdgcn_mfma_f32_16x16x32_bf16(A1, B0, aP10, 0, 0, 0);
    aP11 = __builtin_amdgcn_mfma_f32_16x16x32_bf16(A1, B1, aP11, 0, 0, 0);
    aS0  = __builtin_amdgcn_mfma_f32_16x16x32_bf16(AS, B0, aS0, 0, 0, 0);
    aS1  = __builtin_amdgcn_mfma_f32_16x16x32_bf16(AS, B1, aS1, 0, 0, 0);
}

__device__ __forceinline__ void edge_pass(const unsigned short* __restrict__ hb16,
                                          const int2* __restrict__ edge2,
                                          const float2* wrb2f,
                                          int pb, int pe, int quad, int m,
                                          float w10_0, float w10_1, unsigned selm,
                                          int4 E0, unsigned u0A, unsigned u0B,
                                          f32x4& aP00, f32x4& aP01, f32x4& aP10,
                                          f32x4& aP11, f32x4& aS0, f32x4& aS1) {
    {   // first chunk: jp0 from prefetch, jp1..3 dependent (wave-uniform guards)
        unsigned fa0v[4] = {0,0,0,0}, fa1v[4] = {0,0,0,0}, fasv[4] = {0,0,0,0};
        unsigned fb0v[4] = {0,0,0,0}, fb1v[4] = {0,0,0,0};
        proc_pair(E0, u0A, u0B, wrb2f, w10_0, w10_1, selm, m,
                  fa0v[0], fa1v[0], fasv[0], fb0v[0], fb1v[0]);
        if (pb + 8 < pe) {
            int4 E = *(const int4*)&edge2[pb + 8 + quad * 2];
            unsigned uA, uB; gath(hb16, E, m, uA, uB);
            proc_pair(E, uA, uB, wrb2f, w10_0, w10_1, selm, m,
                      fa0v[1], fa1v[1], fasv[1], fb0v[1], fb1v[1]);
        }
        if (pb + 16 < pe) {
            int4 E = *(const int4*)&edge2[pb + 16 + quad * 2];
            unsigned uA, uB; gath(hb16, E, m, uA, uB);
            proc_pair(E, uA, uB, wrb2f, w10_0, w10_1, selm, m,
                      fa0v[2], fa1v[2], fasv[2], fb0v[2], fb1v[2]);
        }
        if (pb + 24 < pe) {
            int4 E = *(const int4*)&edge2[pb + 24 + quad * 2];
            unsigned uA, uB; gath(hb16, E, m, uA, uB);
            proc_pair(E, uA, uB, wrb2f, w10_0, w10_1, selm, m,
                      fa0v[3], fa1v[3], fasv[3], fb0v[3], fb1v[3]);
        }
        mfma6(fa0v, fa1v, fasv, fb0v, fb1v, aP00, aP01, aP10, aP11, aS0, aS1);
    }
    for (int c0 = pb + 32; c0 < pe; c0 += 32) {   // rare (pdeg > 32)
        unsigned fa0v[4] = {0,0,0,0}, fa1v[4] = {0,0,0,0}, fasv[4] = {0,0,0,0};
        unsigned fb0v[4] = {0,0,0,0}, fb1v[4] = {0,0,0,0};
        #pragma unroll
        for (int jp = 0; jp < 4; ++jp) {
            if (c0 + jp * 8 < pe) {
                int4 E = *(const int4*)&edge2[c0 + jp * 8 + quad * 2];
                unsigned uA, uB; gath(hb16, E, m, uA, uB);
                proc_pair(E, uA, uB, wrb2f, w10_0, w10_1, selm, m,
                          fa0v[jp], fa1v[jp], fasv[jp], fb0v[jp], fb1v[jp]);
            }
        }
        mfma6(fa0v, fa1v, fasv, fb0v, fb1v, aP00, aP01, aP10, aP11, aS0, aS1);
    }
}

__device__ __forceinline__ void stage_node(unsigned short* __restrict__ P, int quad, int m,
                                           float idg, const float* __restrict__ invcnt_n,
                                           const unsigned short* __restrict__ hb16row,
                                           const f32x4& aP00, const f32x4& aP01,
                                           const f32x4& aP10, const f32x4& aP11,
                                           const f32x4& aS0, const f32x4& aS1) {
    #pragma unroll
    for (int reg = 0; reg < 4; ++reg) {
        const int row = quad * 4 + reg;       // D: row = quad*4+reg, col = m / m+16
        *(unsigned*)&P[row * EMB + 2 * m]        = cvt_pk(aP00[reg] * idg, aP01[reg] * idg);
        *(unsigned*)&P[(row + 16) * EMB + 2 * m] = cvt_pk(aP10[reg] * idg, aP11[reg] * idg);
        if (row <= 8) {                        // S rows: 0 -> Stot(32), 1..8 -> S_r(33..40)
            const float sc = (row == 0) ? idg : invcnt_n[row - 1];
            *(unsigned*)&P[(32 + row) * EMB + 2 * m] = cvt_pk(aS0[reg] * sc, aS1[reg] * sc);
        }
    }
    if (quad < 2) {                            // rows 41/42: h_dst direct from bf16 shadow
        unsigned hh = *(const unsigned*)(hb16row + 2 * m);
        *(unsigned*)&P[(41 + quad) * EMB + 2 * m] = hh;
    }
}

__global__ __launch_bounds__(512, 6) void layer_kernel(
    const float* __restrict__ h,
    const unsigned short* __restrict__ hb16,
    const int2* __restrict__ edge2,
    const int4* __restrict__ wavetab,
    const float* __restrict__ invdeg,
    const float* __restrict__ invcnt,
    const float* __restrict__ W1,
    const float* __restrict__ b1,
    const unsigned short* __restrict__ WBs,   // rows 0..32 (W2^T, b2^T)
    const unsigned short* __restrict__ WBl,   // rows 33..42
    const float* __restrict__ rgcnBias_l,
    const float* __restrict__ nnBias_l,
    float* __restrict__ hout,
    unsigned short* __restrict__ hb16out,
    int last)
{
    __shared__ __align__(16) unsigned short P_lds[NPB * KROWS * EMB];  // 44032 B
    __shared__ __align__(16) float2 wrb2f[NREL * 16];                  // 1024 B
    // total 45056 B -> 3 blocks/CU

    const int tid = threadIdx.x;
    const int n0 = blockIdx.x * NPB;

    const int l    = tid & 63;
    const int w    = tid >> 6;        // wave 0..7
    const int quad = l >> 4;          // 0..3
    const int m    = l & 15;
    const float w10_0 = W1[m];
    const float w10_1 = W1[m + 16];
    const unsigned selm = (m == 0) ? 0xFFu : (m <= 8 ? (1u << (m - 1)) : 0u);

    // wave schedule: slots hw0 (pass 0) and hw1 (pass 1) from pairperm (balanced totals)
    int4 wt = wavetab[blockIdx.x * 8 + w];
    const int hw0 = wt.x & 0xFF, hw1 = (wt.x >> 8) & 0xFF;
    const int pb0 = wt.y, pe0 = wt.y + (wt.w & 0xFFFF);
    const int pb1 = wt.z, pe1 = wt.z + (int)((unsigned)wt.w >> 16);
    // prefetch BOTH passes' first quad ONLY (live-range budget — R11 spill lesson)
    int4 E0 = *(const int4*)&edge2[pb0 + quad * 2];
    int4 E1 = *(const int4*)&edge2[pb1 + quad * 2];
    unsigned u0A, u0B, u1A, u1B;
    gath(hb16, E0, m, u0A, u0B);
    gath(hb16, E1, m, u1A, u1B);

    // wave-redundant wrb2f init (2 entries/lane covers all 128; identical values across
    // waves -> benign overlap; own-wave lgkmcnt orders reads; NO block barrier needed)
    {
        int r1 = l >> 4, m1 = l & 15;          // entry l
        wrb2f[l] = make_float2(W1[(1 + r1) * EMB + m1] + b1[m1],
                               W1[(1 + r1) * EMB + m1 + 16] + b1[m1 + 16]);
        int e2 = l + 64;
        int r2 = e2 >> 4, m2 = e2 & 15;        // entry l+64
        wrb2f[e2] = make_float2(W1[(1 + r2) * EMB + m2] + b1[m2],
                                W1[(1 + r2) * EMB + m2 + 16] + b1[m2 + 16]);
    }

    {   // pass 0 (slot hw0)
        f32x4 aP00 = {0,0,0,0}, aP01 = {0,0,0,0}, aP10 = {0,0,0,0}, aP11 = {0,0,0,0};
        f32x4 aS0 = {0,0,0,0}, aS1 = {0,0,0,0};
        edge_pass(hb16, edge2, wrb2f, pb0, pe0, quad, m, w10_0, w10_1, selm,
                  E0, u0A, u0B, aP00, aP01, aP10, aP11, aS0, aS1);
        const int n = n0 + hw0;
        stage_node(P_lds + (size_t)hw0 * KROWS * EMB, quad, m, invdeg[n],
                   invcnt + (size_t)n * NREL, hb16 + (size_t)n * EMB,
                   aP00, aP01, aP10, aP11, aS0, aS1);
    }
    {   // pass 1 (slot hw1)
        f32x4 aP00 = {0,0,0,0}, aP01 = {0,0,0,0}, aP10 = {0,0,0,0}, aP11 = {0,0,0,0};
        f32x4 aS0 = {0,0,0,0}, aS1 = {0,0,0,0};
        edge_pass(hb16, edge2, wrb2f, pb1, pe1, quad, m, w10_0, w10_1, selm,
                  E1, u1A, u1B, aP00, aP01, aP10, aP11, aS0, aS1);
        const int n = n0 + hw1;
        stage_node(P_lds + (size_t)hw1 * KROWS * EMB, quad, m, invdeg[n],
                   invcnt + (size_t)n * NREL, hb16 + (size_t)n * EMB,
                   aP00, aP01, aP10, aP11, aS0, aS1);
    }
    __syncthreads();

    // ---------- MFMA contraction (WB k-order matches staged interleaved columns) ----------
    const int node16 = l & 15;
    const int o0 = l & 15;                    // B n-index (tile 0); tile 1 = +16

    f32x4 accN0 = {0,0,0,0}, accN1 = {0,0,0,0};
    f32x4 accR0 = {0,0,0,0}, accR1 = {0,0,0,0};

    #pragma unroll
    for (int j = 0; j < 6; j++) {
        const int rr = w + 8 * j;             // wave-uniform
        if (rr < KROWS) {
            const unsigned short* Bsrc = (rr < 33) ? (WBs + (size_t)rr * 1024)
                                                   : (WBl + (size_t)(rr - 33) * 1024);
            short8 bf0 = *(const short8*)(Bsrc + o0 * 32 + quad * 8);
            short8 bf1 = *(const short8*)(Bsrc + (o0 + 16) * 32 + quad * 8);
            short8 a = *(const short8*)&P_lds[(size_t)node16 * KROWS * EMB + rr * EMB + quad * 8];
            if (rr <= 32 || rr == 42) {
                accN0 = __builtin_amdgcn_mfma_f32_16x16x32_bf16(a, bf0, accN0, 0, 0, 0);
                accN1 = __builtin_amdgcn_mfma_f32_16x16x32_bf16(a, bf1, accN1, 0, 0, 0);
            } else {
                accR0 = __builtin_amdgcn_mfma_f32_16x16x32_bf16(a, bf0, accR0, 0, 0, 0);
                accR1 = __builtin_amdgcn_mfma_f32_16x16x32_bf16(a, bf1, accR1, 0, 0, 0);
            }
        }
    }
    __syncthreads();                          // all A-reads done; safe to overlay RedAll

    // ---------- deterministic cross-wave reduction (no atomics) ----------
    float* RedAll = (float*)&P_lds[0];        // 8 waves x 1024 floats = 32 KiB < 44 KiB
    {
        float* my = RedAll + w * 1024;
        #pragma unroll
        for (int reg = 0; reg < 4; reg++) {
            int nd = quad * 4 + reg;          // C/D: row(m=node)=quad*4+reg, col(n=o)=lane&15
            my[nd * 32 + o0]            = accN0[reg];
            my[nd * 32 + o0 + 16]       = accN1[reg];
            my[512 + nd * 32 + o0]      = accR0[reg];
            my[512 + nd * 32 + o0 + 16] = accR1[reg];
        }
    }
    __syncthreads();

    // ---------- epilogue (slot = tid>>5, node = n0+slot CONSECUTIVE, col = tid&31) ----------
    {
        const int hw2 = tid >> 5, lane = tid & 31;
        const int n2 = n0 + hw2;
        float sn = 0.0f, sr = 0.0f;
        #pragma unroll
        for (int ww = 0; ww < 8; ww++) {
            sn += RedAll[ww * 1024 + tid];          // stride-1, conflict-free
            sr += RedAll[ww * 1024 + 512 + tid];
        }
        const int il = ((lane & 15) << 1) | (lane >> 4);
        float hd = h[(size_t)n2 * EMB + il];
        float o_r = fmaxf(sr + rgcnBias_l[lane], 0.0f);
        float o_n = fmaxf(sn + nnBias_l[lane], 0.0f);
        float outv = hd + o_r + o_n;
        hout[(size_t)n2 * EMB + (last ? lane : il)] = outv;
        if (!last) {                               // bf16 shadow for next layer's gathers
            float pv = __shfl_down(outv, 16, 32);  // col lane+16 (32-lane segs node-aligned)
            unsigned pk = cvt_pk(outv, pv);
            if (lane < 16)
                *(unsigned*)&hb16out[(size_t)n2 * EMB + 2 * lane] = pk;
        }
    }
}

// ---------------- launch ----------------

extern "C" void kernel_launch(void* const* d_in, const int* in_sizes, int n_in,
                              void* d_out, int out_size, void* d_ws, size_t ws_size,
                              hipStream_t stream) {
    const float* x        = (const float*)d_in[0];
    const int*   ei       = (const int*)d_in[1];
    const int*   et       = (const int*)d_in[2];
    const float* ed       = (const float*)d_in[3];
    const float* fcW      = (const float*)d_in[4];
    const float* fcb      = (const float*)d_in[5];
    const float* rgcnW    = (const float*)d_in[6];
    const float* rgcnRoot = (const float*)d_in[7];
    const float* rgcnBias = (const float*)d_in[8];
    const float* W1       = (const float*)d_in[9];
    const float* b1       = (const float*)d_in[10];
    const float* W2       = (const float*)d_in[11];
    const float* b2       = (const float*)d_in[12];
    const float* nnRoot   = (const float*)d_in[13];
    const float* nnBias   = (const float*)d_in[14];

    float* ws = (float*)d_ws;
    float* h_a    = ws;  ws += (size_t)(N_NODES + 1) * EMB;
    float* h_b    = ws;  ws += (size_t)(N_NODES + 1) * EMB;
    unsigned short* hb16_a = (unsigned short*)ws;  ws += (size_t)(N_NODES + 1) * EMB / 2;
    unsigned short* hb16_b = (unsigned short*)ws;  ws += (size_t)(N_NODES + 1) * EMB / 2;
    float* invdeg = ws;  ws += (size_t)N_NODES;
    float* invcnt = ws;  ws += (size_t)N_NODES * NREL;
    unsigned short* WB = (unsigned short*)ws;  ws += (size_t)83 * 1024 / 2;
    int2* edge2   = (int2*)ws;     ws += (size_t)E2CAP * 2;
    int* row_ptr  = (int*)ws;      ws += (size_t)(N_NODES + 1);
    int* bsum     = (int*)ws;      ws += (size_t)NCHUNK;
    int* boff     = (int*)ws;      ws += (size_t)NCHUNK;
    int* deg      = (int*)ws;      ws += (size_t)N_NODES;     // written by nodeprep (no zero)
    int* relcnt   = (int*)ws;      ws += (size_t)N_NODES * NREL;  // relcnt..cursor zeroed (9N)
    int* cursor   = (int*)ws;      ws += (size_t)N_NODES;
    unsigned char* perm = (unsigned char*)ws;  ws += (size_t)(NBLK * NPB + 3) / 4;
    int4* wavetab = (int4*)ws;     ws += (size_t)NBLK * 8 * 4;
    (void)in_sizes; (void)n_in; (void)out_size; (void)ws_size;

    setup0_kernel<<<FCB + FILLB + WTBFB, 256, 0, stream>>>(
        x, fcW, fcb, h_a, hb16_a, relcnt,
        (unsigned*)(hb16_a + (size_t)N_NODES * EMB),
        (unsigned*)(hb16_b + (size_t)N_NODES * EMB),
        W2, b2, rgcnW, rgcnRoot, nnRoot, WB);
    hist_kernel<<<(N_EDGES + 255) / 256, 256, 0, stream>>>(ei, et, relcnt);
    nodeprep_kernel<<<NCHUNK, 256, 0, stream>>>(relcnt, deg, bsum, invdeg, invcnt, perm);
    boff_kernel<<<1, 256, 0, stream>>>(bsum, boff, row_ptr);
    rptr_kernel<<<NCHUNK, 256, 0, stream>>>(deg, boff, row_ptr);
    scatter_kernel<<<(N_EDGES + 255) / 256, 256, 0, stream>>>(ei, et, ed, row_ptr, deg,
                                                              cursor, edge2, perm, wavetab);

    const float* hin = h_a;
    const unsigned short* hbin = hb16_a;
    float* houtb = h_b;
    unsigned short* hboutb = hb16_b;
    for (int l = 0; l < NLAYER; l++) {
        int last = (l == NLAYER - 1) ? 1 : 0;
        float* dst = last ? (float*)d_out : houtb;
        layer_kernel<<<NBLK, 512, 0, stream>>>(
            hin, hbin, edge2, wavetab, invdeg, invcnt, W1, b1,
            WB, WB + (size_t)(33 + l * 10) * 1024,
            rgcnBias + (size_t)l * EMB,
            nnBias + (size_t)l * EMB,
            dst, hboutb, last);
        float* old_in = (float*)hin;
        unsigned short* old_hb = (unsigned short*)hbin;
        hin = dst; hbin = hboutb;
        houtb = old_in; hboutb = old_hb;
    }
}